// Round 3
// baseline (22956.152 us; speedup 1.0000x reference)
//
#include <hip/hip_runtime.h>

// ---------------------------------------------------------------------------
// FastSpeech-style encoder, round 2: runtime dtype detection (fp32 vs bf16
// float tensors), canonical bf16 weights in ws, ~65 MB workspace, chunked.
// B=32 T=1024 D=256 NH=2 dk=128 D_HID=1024 L=4, conv1 k=9 pad=4, conv2 k=1.
// ---------------------------------------------------------------------------

#define B_ 32
#define T_ 1024
#define D_ 256
#define NH_ 2
#define DK_ 128
#define DH_ 1024
#define L_ 4
#define MROWS (B_ * T_)        // 32768
#define KCONV (D_ * 9)         // 2304
#define CHB_ 8                 // batches per chunk
#define CHR_ (CHB_ * T_)       // 8192 rows per chunk
#define NCH_ (B_ / CHB_)       // 4 chunks

typedef unsigned short u16;

__device__ __forceinline__ float bf2f(u16 h) {
    union { unsigned int u; float f; } a;
    a.u = ((unsigned int)h) << 16;
    return a.f;
}

__device__ __forceinline__ u16 f2bf(float f) {
    union { float f; unsigned int u; } a;
    a.f = f;
    unsigned int r = a.u + 0x7fffu + ((a.u >> 16) & 1u);  // RNE
    return (u16)(r >> 16);
}

// --------------------------- dtype detection -------------------------------
// word_emb row 0 is exactly zero (padding_idx=0).
// u16 words [256..511] of the raw buffer:
//   bf16 layout -> row 1 (nonzero gaussians) ;  fp32 layout -> row 0 tail (zeros)
__global__ void detect_kernel(const void* wemb_raw, int* flag) {
    __shared__ int cnt;
    if (threadIdx.x == 0) cnt = 0;
    __syncthreads();
    const u16* p = (const u16*)wemb_raw;
    if (p[256 + threadIdx.x] != 0) atomicAdd(&cnt, 1);
    __syncthreads();
    if (threadIdx.x == 0) *flag = (cnt >= 128) ? 1 : 0;   // 1 = bf16, 0 = fp32
}

// raw (fp32 or bf16 per flag) -> canonical bf16
__global__ void cvt_any_kernel(const void* __restrict__ src, u16* __restrict__ dst,
                               int n, const int* __restrict__ flag) {
    int i = blockIdx.x * 256 + threadIdx.x;
    if (i >= n) return;
    if (*flag) dst[i] = ((const u16*)src)[i];
    else       dst[i] = f2bf(((const float*)src)[i]);
}

// conv1 weights (one layer) [oc=1024][ic=256][kpos=9] -> [oc][kpos*256+ic] bf16
__global__ void w1_reorder_kernel(const void* __restrict__ src, u16* __restrict__ out,
                                  int n, const int* __restrict__ flag) {
    int idx = blockIdx.x * 256 + threadIdx.x;
    if (idx >= n) return;
    int oc = idx / KCONV;
    int kk = idx % KCONV;
    int kpos = kk >> 8;
    int ic   = kk & 255;
    int si = (oc * D_ + ic) * 9 + kpos;
    if (*flag) out[idx] = ((const u16*)src)[si];
    else       out[idx] = f2bf(((const float*)src)[si]);
}

__global__ void sentinel_kernel(void* out, int out_size) {
    int i = blockIdx.x * 256 + threadIdx.x;
    if (i < out_size) ((u16*)out)[i] = 0x42F6;  // 123.0 in bf16 — "ws too small"
}

// --------------------------- small utility kernels -------------------------

__global__ void embed_kernel(const int* __restrict__ seq, const int* __restrict__ pos,
                             const u16* __restrict__ wemb, const u16* __restrict__ pemb,
                             float* __restrict__ X, float* __restrict__ NP) {
    int row = blockIdx.x;       // 0..32767
    int d   = threadIdx.x;      // 0..255
    int s = seq[row];
    int p = pos[row];
    X[(size_t)row * D_ + d] = bf2f(wemb[s * D_ + d]) + bf2f(pemb[p * D_ + d]);
    if (d == 0) NP[row] = (s != 0) ? 1.0f : 0.0f;
}

// LN: X fp32 -> out bf16 (canonical gamma/beta bf16)
__global__ __launch_bounds__(256)
void ln_kernel(const float* __restrict__ x, const u16* __restrict__ g,
               const u16* __restrict__ bta, u16* __restrict__ out) {
    int row = blockIdx.x;
    int d   = threadIdx.x;
    float v = x[(size_t)row * D_ + d];
    float s = v, s2 = v * v;
#pragma unroll
    for (int off = 32; off; off >>= 1) {
        s  += __shfl_down(s, off, 64);
        s2 += __shfl_down(s2, off, 64);
    }
    __shared__ float w1s[4], w2s[4];
    __shared__ float mb, rb;
    int wv = d >> 6;
    if ((d & 63) == 0) { w1s[wv] = s; w2s[wv] = s2; }
    __syncthreads();
    if (d == 0) {
        float t1 = w1s[0] + w1s[1] + w1s[2] + w1s[3];
        float t2 = w2s[0] + w2s[1] + w2s[2] + w2s[3];
        float m   = t1 * (1.0f / 256.0f);
        float var = t2 * (1.0f / 256.0f) - m * m;
        mb = m;
        rb = rsqrtf(var + 1e-5f);
    }
    __syncthreads();
    out[(size_t)row * D_ + d] = f2bf((v - mb) * rb * bf2f(g[d]) + bf2f(bta[d]));
}

__global__ void out_kernel(const float* __restrict__ X, const float* __restrict__ NP,
                           void* __restrict__ out, int out_size,
                           const int* __restrict__ flag) {
    int i = blockIdx.x * 256 + threadIdx.x;
    if (i >= out_size) return;
    const int n1 = MROWS * D_;
    float v = (i < n1) ? X[i] : NP[i - n1];
    if (*flag) ((u16*)out)[i] = f2bf(v);
    else       ((float*)out)[i] = v;
}

// ------------------------------- GEMM --------------------------------------
// C[M,N] = A[M,K] @ Bw^T (+bias) (relu?) (+resid) (*mask_row).
// A, Bw, bias: bf16. resid/mask: fp32. C: bf16 if CBF16 else fp32.
// Bw is [N][K] row-major. 64x64 tile, BK=16, 256 threads, 4x4 per thread.
// IM2COL: A is H-chunk [CHR][256] (batch-aligned); A(m, kk=kpos*256+ic) =
// A[m+kpos-4][ic] with zero time-padding (t = m & 1023).
template <bool IM2COL, bool CBF16>
__global__ __launch_bounds__(256)
void gemm_k(const u16* __restrict__ A, const u16* __restrict__ Bw,
            const u16* __restrict__ bias, const float* resid,
            const float* __restrict__ mask, void* Cp,
            int M, int N, int K, int relu) {
    __shared__ float As[16][68];
    __shared__ float Bs[16][68];
    const int tid = threadIdx.x;
    const int tx = tid & 15;   // n
    const int ty = tid >> 4;   // m
    const int m0 = blockIdx.y * 64;
    const int n0 = blockIdx.x * 64;
    const int lk = tid & 15;
    const int lr = tid >> 4;
    float c[4][4] = {};
    for (int kt = 0; kt < K; kt += 16) {
#pragma unroll
        for (int i = 0; i < 4; i++) {
            int row = lr + i * 16;
            int kk  = kt + lk;
            float av;
            if (IM2COL) {
                int m    = m0 + row;
                int kpos = kk >> 8;
                int ic   = kk & 255;
                int st   = (m & (T_ - 1)) + kpos - 4;
                av = (st >= 0 && st < T_) ? bf2f(A[(m + kpos - 4) * D_ + ic]) : 0.0f;
            } else {
                av = bf2f(A[(size_t)(m0 + row) * K + kk]);
            }
            As[lk][row] = av;
            Bs[lk][row] = bf2f(Bw[(size_t)(n0 + row) * K + kk]);
        }
        __syncthreads();
#pragma unroll
        for (int kk = 0; kk < 16; kk++) {
            float4 a4 = *(const float4*)&As[kk][ty * 4];
            float4 b4 = *(const float4*)&Bs[kk][tx * 4];
            float a[4] = {a4.x, a4.y, a4.z, a4.w};
            float b[4] = {b4.x, b4.y, b4.z, b4.w};
#pragma unroll
            for (int i = 0; i < 4; i++)
#pragma unroll
                for (int j = 0; j < 4; j++) c[i][j] += a[i] * b[j];
        }
        __syncthreads();
    }
#pragma unroll
    for (int i = 0; i < 4; i++) {
        int m = m0 + ty * 4 + i;
        float mk = mask ? mask[m] : 1.0f;
        float o[4];
#pragma unroll
        for (int j = 0; j < 4; j++) {
            float v = c[i][j];
            if (bias) v += bf2f(bias[n0 + tx * 4 + j]);
            if (relu) v = fmaxf(v, 0.0f);
            o[j] = v;
        }
        if (resid) {
            float4 rv = *(const float4*)&resid[(size_t)m * N + n0 + tx * 4];
            o[0] += rv.x; o[1] += rv.y; o[2] += rv.z; o[3] += rv.w;
        }
        if (mask) { o[0] *= mk; o[1] *= mk; o[2] *= mk; o[3] *= mk; }
        if (CBF16) {
            u16* C = (u16*)Cp;
            ushort4 pk;
            pk.x = f2bf(o[0]); pk.y = f2bf(o[1]); pk.z = f2bf(o[2]); pk.w = f2bf(o[3]);
            *(ushort4*)&C[(size_t)m * N + n0 + tx * 4] = pk;
        } else {
            float* C = (float*)Cp;
            *(float4*)&C[(size_t)m * N + n0 + tx * 4] =
                make_float4(o[0], o[1], o[2], o[3]);
        }
    }
}

// ----------------------------- attention -----------------------------------
// One block per (chunk-local b, head, 8-query tile). QKV: bf16 [CHR][768]
// (q|k|v; head h = cols h*128..). npad: fp32, chunk-offset. O: bf16 [CHR][256].
__global__ __launch_bounds__(256)
void attn_kernel(const u16* __restrict__ QKV, const float* __restrict__ npad,
                 u16* __restrict__ O) {
    __shared__ float Qs[8][132];
    __shared__ float KV[32][132];
    __shared__ float S[8][1024];
    const int tid = threadIdx.x;
    const int qt = blockIdx.x;   // 0..127
    const int h  = blockIdx.y;   // 0..1
    const int b  = blockIdx.z;   // chunk-local batch
    const int q0 = qt * 8;
    const size_t base = (size_t)b * T_;

    for (int e = tid; e < 8 * 128; e += 256) {
        int q = e >> 7, d = e & 127;
        Qs[q][d] = bf2f(QKV[(base + q0 + q) * 768 + h * DK_ + d]);
    }
    const float scale = 0.08838834764831845f;  // 1/sqrt(128)
    const int k_local = tid & 31;
    const int qs = tid >> 5;  // 0..7
    for (int kt = 0; kt < 32; kt++) {
        __syncthreads();
        for (int e = tid; e < 32 * 128; e += 256) {
            int k = e >> 7, d = e & 127;
            KV[k][d] = bf2f(QKV[(base + kt * 32 + k) * 768 + 256 + h * DK_ + d]);
        }
        __syncthreads();
        float s = 0.0f;
#pragma unroll
        for (int d = 0; d < 128; d += 4) {
            float4 qv = *(const float4*)&Qs[qs][d];
            float4 kv = *(const float4*)&KV[k_local][d];
            s += qv.x * kv.x + qv.y * kv.y + qv.z * kv.z + qv.w * kv.w;
        }
        s *= scale;
        if (npad[base + kt * 32 + k_local] == 0.0f) s = -1e30f;
        S[qs][kt * 32 + k_local] = s;
    }
    __syncthreads();
    {   // softmax, 32 lanes per row
        const int q = tid >> 5;
        const int j = tid & 31;
        float mx = -1e30f;
        for (int k = j; k < 1024; k += 32) mx = fmaxf(mx, S[q][k]);
#pragma unroll
        for (int off = 16; off; off >>= 1) mx = fmaxf(mx, __shfl_xor(mx, off, 32));
        float sum = 0.0f;
        for (int k = j; k < 1024; k += 32) {
            float e = __expf(S[q][k] - mx);
            S[q][k] = e;
            sum += e;
        }
#pragma unroll
        for (int off = 16; off; off >>= 1) sum += __shfl_xor(sum, off, 32);
        float inv = 1.0f / sum;
        for (int k = j; k < 1024; k += 32) S[q][k] *= inv;
    }
    // PV
    const int d_local = tid & 127;
    const int qb = tid >> 7;  // 0..1; thread owns q = qb, qb+2, qb+4, qb+6
    float o[4] = {0, 0, 0, 0};
    for (int kt = 0; kt < 32; kt++) {
        __syncthreads();
        for (int e = tid; e < 32 * 128; e += 256) {
            int k = e >> 7, d = e & 127;
            KV[k][d] = bf2f(QKV[(base + kt * 32 + k) * 768 + 512 + h * DK_ + d]);
        }
        __syncthreads();
#pragma unroll
        for (int k4 = 0; k4 < 32; k4 += 4) {
            float4 p[4];
#pragma unroll
            for (int qq = 0; qq < 4; qq++)
                p[qq] = *(const float4*)&S[qb + qq * 2][kt * 32 + k4];
#pragma unroll
            for (int u = 0; u < 4; u++) {
                float vv = KV[k4 + u][d_local];
                o[0] += ((const float*)&p[0])[u] * vv;
                o[1] += ((const float*)&p[1])[u] * vv;
                o[2] += ((const float*)&p[2])[u] * vv;
                o[3] += ((const float*)&p[3])[u] * vv;
            }
        }
    }
#pragma unroll
    for (int qq = 0; qq < 4; qq++)
        O[(base + q0 + qb + qq * 2) * D_ + h * DK_ + d_local] = f2bf(o[qq]);
}

// ------------------------------- driver ------------------------------------

static inline int cdiv(int a, int b) { return (a + b - 1) / b; }

extern "C" void kernel_launch(void* const* d_in, const int* in_sizes, int n_in,
                              void* d_out, int out_size, void* d_ws, size_t ws_size,
                              hipStream_t stream) {
    const int* seq = (const int*)d_in[0];
    const int* pos = (const int*)d_in[1];
    (void)in_sizes; (void)n_in;

    // ---------------- workspace layout (bytes) ----------------
    unsigned char* w = (unsigned char*)d_ws;
    size_t off = 0;
    auto take = [&](size_t bytes) {
        unsigned char* p = w + off;
        off += (bytes + 255) & ~(size_t)255;
        return p;
    };
    int*   FLAG = (int*)  take(4);
    float* X    = (float*)take((size_t)MROWS * D_ * 4);   // 33.55 MB
    float* NP   = (float*)take((size_t)MROWS * 4);        //  0.13 MB
    u16*   HC   = (u16*)  take((size_t)CHR_ * D_ * 2);    //  4.19 MB
    u16*   SCR  = (u16*)  take((size_t)CHR_ * DH_ * 2);   // 16.78 MB
    u16*   W1RC = (u16*)  take((size_t)DH_ * KCONV * 2);  //  4.72 MB
    u16*   WEMB = (u16*)  take((size_t)300 * D_ * 2);
    u16*   PEMB = (u16*)  take((size_t)3001 * D_ * 2);
    u16*   QKVW = (u16*)  take((size_t)L_ * 3 * D_ * D_ * 2);
    u16*   QKVB = (u16*)  take((size_t)L_ * 3 * D_ * 2);
    u16*   FCW  = (u16*)  take((size_t)L_ * D_ * D_ * 2);
    u16*   FCB  = (u16*)  take((size_t)L_ * D_ * 2);
    u16*   G1c  = (u16*)  take((size_t)L_ * D_ * 2);
    u16*   B1c  = (u16*)  take((size_t)L_ * D_ * 2);
    u16*   C1B  = (u16*)  take((size_t)L_ * DH_ * 2);
    u16*   C2W  = (u16*)  take((size_t)L_ * D_ * DH_ * 2);
    u16*   C2B  = (u16*)  take((size_t)L_ * D_ * 2);
    u16*   G2c  = (u16*)  take((size_t)L_ * D_ * 2);
    u16*   B2c  = (u16*)  take((size_t)L_ * D_ * 2);

    if (off > ws_size) {  // distinctive failure signature: out = 123.0
        sentinel_kernel<<<cdiv(out_size, 256), 256, 0, stream>>>(d_out, out_size);
        return;
    }

    detect_kernel<<<1, 256, 0, stream>>>(d_in[2], FLAG);

    auto cvt = [&](const void* src, u16* dst, int n) {
        cvt_any_kernel<<<cdiv(n, 256), 256, 0, stream>>>(src, dst, n, FLAG);
    };
    cvt(d_in[2],  WEMB, 300 * D_);
    cvt(d_in[3],  PEMB, 3001 * D_);
    cvt(d_in[4],  QKVW, L_ * 3 * D_ * D_);
    cvt(d_in[5],  QKVB, L_ * 3 * D_);
    cvt(d_in[6],  FCW,  L_ * D_ * D_);
    cvt(d_in[7],  FCB,  L_ * D_);
    cvt(d_in[8],  G1c,  L_ * D_);
    cvt(d_in[9],  B1c,  L_ * D_);
    cvt(d_in[11], C1B,  L_ * DH_);
    cvt(d_in[12], C2W,  L_ * D_ * DH_);
    cvt(d_in[13], C2B,  L_ * D_);
    cvt(d_in[14], G2c,  L_ * D_);
    cvt(d_in[15], B2c,  L_ * D_);

    embed_kernel<<<MROWS, 256, 0, stream>>>(seq, pos, WEMB, PEMB, X, NP);

    for (int l = 0; l < L_; l++) {
        // ---- attention sub-layer (chunked) ----
        for (int c = 0; c < NCH_; c++) {
            const size_t ro = (size_t)c * CHR_;
            ln_kernel<<<CHR_, 256, 0, stream>>>(X + ro * D_, G1c + l * D_, B1c + l * D_, HC);
            gemm_k<false, true><<<dim3(768 / 64, CHR_ / 64), 256, 0, stream>>>(
                HC, QKVW + (size_t)l * 3 * D_ * D_, QKVB + l * 3 * D_,
                nullptr, nullptr, SCR, CHR_, 3 * D_, D_, 0);
            attn_kernel<<<dim3(T_ / 8, NH_, CHB_), 256, 0, stream>>>(
                SCR, NP + ro, HC);
            gemm_k<false, false><<<dim3(D_ / 64, CHR_ / 64), 256, 0, stream>>>(
                HC, FCW + (size_t)l * D_ * D_, FCB + l * D_,
                X + ro * D_, NP + ro, X + ro * D_, CHR_, D_, D_, 0);
        }
        // ---- conv FFN sub-layer (chunked) ----
        {
            int n = DH_ * KCONV;
            const void* src = (*(const u16*)nullptr, (const void*)nullptr);  // placeholder avoided below
            (void)src;
        }
        {
            int n = DH_ * KCONV;
            // raw conv1 weights for layer l: element offset l*DH*D*9 (same count
            // in fp32 or bf16; byte offset differs — handle inside by passing
            // a raw byte pointer adjusted per flag is impossible host-side, so
            // pass the base and layer index via element math in the kernel call:
            // we instead pass src already offset in ELEMENTS for each dtype via
            // two pointers and let the kernel pick — simpler: offset in kernel.
            w1_reorder_kernel<<<cdiv(n, 256), 256, 0, stream>>>(
                (const void*)((const char*)d_in[10]), W1RC, n, FLAG);
            // NOTE: layer offset handled below via pointer fixup kernel-side is
            // not possible; instead we rely on the fact that we re-launch per
            // layer with an element offset encoded here:
            (void)n;
        }
        // Apply the layer offset correctly: re-launch with element-offset
        // pointers for both possible dtypes. We overwrite the above launch's
        // result only when l > 0 is wrong — to keep it simple and correct, the
        // reorder below uses byte offsets per dtype chosen by a dedicated
        // kernel reading FLAG:
        {
            int n = DH_ * KCONV;
            // second launch with explicit per-layer source pointers
            // (kernel reads flag; fp32 path uses f32 base, bf16 path u16 base)
            struct { const float* f; const u16* h; } srcs = {
                (const float*)d_in[10] + (size_t)l * DH_ * D_ * 9,
                (const u16*)d_in[10] + (size_t)l * DH_ * D_ * 9 };
            // Use a small wrapper kernel via cvt-style dual pointers:
            // reuse w1_reorder with the flag-appropriate pointer is host-side
            // impossible; so we pass BOTH and let a dedicated kernel choose.
            extern __global__ void w1_reorder2_kernel(const float*, const u16*,
                                                      u16*, int, const int*);
            w1_reorder2_kernel<<<cdiv(n, 256), 256, 0, stream>>>(
                srcs.f, srcs.h, W1RC, n, FLAG);
        }
        for (int c = 0; c < NCH_; c++) {
            const size_t ro = (size_t)c * CHR_;
            ln_kernel<<<CHR_, 256, 0, stream>>>(X + ro * D_, G2c + l * D_, B2c + l * D_, HC);
            gemm_k<true, true><<<dim3(DH_ / 64, CHR_ / 64), 256, 0, stream>>>(
                HC, W1RC, C1B + l * DH_,
                nullptr, nullptr, SCR, CHR_, DH_, KCONV, 1);
            gemm_k<false, false><<<dim3(D_ / 64, CHR_ / 64), 256, 0, stream>>>(
                SCR, C2W + (size_t)l * D_ * DH_, C2B + l * D_,
                X + ro * D_, NP + ro, X + ro * D_, CHR_, D_, DH_, 0);
        }
    }

    out_kernel<<<cdiv(out_size, 256), 256, 0, stream>>>(X, NP, d_out, out_size, FLAG);
}

// dual-pointer conv1 reorder: picks fp32 or bf16 source per flag
__global__ void w1_reorder2_kernel(const float* __restrict__ srcf,
                                   const u16* __restrict__ srch,
                                   u16* __restrict__ out, int n,
                                   const int* __restrict__ flag) {
    int idx = blockIdx.x * 256 + threadIdx.x;
    if (idx >= n) return;
    int oc = idx / KCONV;
    int kk = idx % KCONV;
    int kpos = kk >> 8;
    int ic   = kk & 255;
    int si = (oc * D_ + ic) * 9 + kpos;
    out[idx] = (*flag) ? srch[si] : f2bf(srcf[si]);
}

// Round 4
// 3391.298 us; speedup vs baseline: 6.7691x; 6.7691x over previous
//
#include <hip/hip_runtime.h>

// ---------------------------------------------------------------------------
// FastSpeech-style encoder, round 3: MFMA everywhere.
// B=32 T=1024 D=256 NH=2 dk=128 D_HID=1024 L=4, conv1 k=9 pad=4, conv2 k=1.
// fp32 inputs detected at runtime -> canonical bf16 weights; X kept fp32.
// GEMMs: 128x128 tile, BK=32, mfma_f32_16x16x32_bf16, global_load_lds(16B).
// Attention: flash-style MFMA, 64q x 64k tiles, online softmax.
// ---------------------------------------------------------------------------

#define B_ 32
#define T_ 1024
#define D_ 256
#define NH_ 2
#define DK_ 128
#define DH_ 1024
#define L_ 4
#define MROWS (B_ * T_)        // 32768
#define KCONV (D_ * 9)         // 2304
#define CHB_ 8                 // batches per chunk
#define CHR_ (CHB_ * T_)       // 8192 rows per chunk
#define NCH_ (B_ / CHB_)       // 4 chunks
#define TPAD 1032              // 4 zero + 1024 + 4 zero rows per batch (Hpad)

typedef unsigned short u16;
typedef short bf16x8 __attribute__((ext_vector_type(8)));
typedef float f32x4 __attribute__((ext_vector_type(4)));
typedef u16 u16x8 __attribute__((ext_vector_type(8)));

__device__ __forceinline__ float bf2f(u16 h) {
    union { unsigned int u; float f; } a;
    a.u = ((unsigned int)h) << 16;
    return a.f;
}

__device__ __forceinline__ u16 f2bf(float f) {
    union { float f; unsigned int u; } a;
    a.f = f;
    unsigned int r = a.u + 0x7fffu + ((a.u >> 16) & 1u);  // RNE
    return (u16)(r >> 16);
}

__device__ __forceinline__ void glds16(const u16* g, u16* l) {
    __builtin_amdgcn_global_load_lds(
        (const __attribute__((address_space(1))) void*)g,
        (__attribute__((address_space(3))) void*)l, 16, 0, 0);
}

// --------------------------- dtype detection -------------------------------
__global__ void detect_kernel(const void* wemb_raw, int* flag) {
    __shared__ int cnt;
    if (threadIdx.x == 0) cnt = 0;
    __syncthreads();
    const u16* p = (const u16*)wemb_raw;
    if (p[256 + threadIdx.x] != 0) atomicAdd(&cnt, 1);
    __syncthreads();
    if (threadIdx.x == 0) *flag = (cnt >= 128) ? 1 : 0;   // 1 = bf16, 0 = fp32
}

__global__ void cvt_any_kernel(const void* __restrict__ src, u16* __restrict__ dst,
                               int n, const int* __restrict__ flag) {
    int i = blockIdx.x * 256 + threadIdx.x;
    if (i >= n) return;
    if (*flag) dst[i] = ((const u16*)src)[i];
    else       dst[i] = f2bf(((const float*)src)[i]);
}

// conv1 weights (one layer) [oc][ic=256][kpos=9] -> [oc][kpos*256+ic] bf16
__global__ void w1_reorder2_kernel(const float* __restrict__ srcf,
                                   const u16* __restrict__ srch,
                                   u16* __restrict__ out, int n,
                                   const int* __restrict__ flag) {
    int idx = blockIdx.x * 256 + threadIdx.x;
    if (idx >= n) return;
    int oc = idx / KCONV;
    int kk = idx % KCONV;
    int kpos = kk >> 8;
    int ic   = kk & 255;
    int si = (oc * D_ + ic) * 9 + kpos;
    out[idx] = (*flag) ? srch[si] : f2bf(srcf[si]);
}

__global__ void sentinel_kernel(void* out, int out_size) {
    int i = blockIdx.x * 256 + threadIdx.x;
    if (i < out_size) ((u16*)out)[i] = 0x42F6;  // 123.0 bf16 — "ws too small"
}

// --------------------------- small utility kernels -------------------------

__global__ void embed_kernel(const int* __restrict__ seq, const int* __restrict__ pos,
                             const u16* __restrict__ wemb, const u16* __restrict__ pemb,
                             float* __restrict__ X, float* __restrict__ NP) {
    int row = blockIdx.x;
    int d   = threadIdx.x;
    int s = seq[row];
    int p = pos[row];
    X[(size_t)row * D_ + d] = bf2f(wemb[s * D_ + d]) + bf2f(pemb[p * D_ + d]);
    if (d == 0) NP[row] = (s != 0) ? 1.0f : 0.0f;
}

// zero the 4-row borders of each batch in Hpad (rows 0..3 and 1028..1031)
__global__ void zero_pad_kernel(u16* __restrict__ Hp) {
    int i = blockIdx.x * 256 + threadIdx.x;          // CHB*8*256 = 16384
    if (i >= CHB_ * 8 * 256) return;
    int b = i / (8 * 256);
    int r = (i / 256) & 7;
    int d = i & 255;
    int row = (r < 4) ? r : (1024 + r);
    Hp[(size_t)(b * TPAD + row) * D_ + d] = 0;
}

// LN: 4 rows/block (1 wave per row). x chunk-local [8192][256] fp32;
// out written to Hpad layout: row -> (row>>10)*TPAD + 4 + (row&1023).
__global__ __launch_bounds__(256)
void ln_kernel(const float* __restrict__ x, const u16* __restrict__ g,
               const u16* __restrict__ bta, u16* __restrict__ outp) {
    int wave = threadIdx.x >> 6, lane = threadIdx.x & 63;
    int row = blockIdx.x * 4 + wave;
    const float* xr = x + (size_t)row * D_;
    float4 v = *(const float4*)&xr[lane * 4];
    float s  = v.x + v.y + v.z + v.w;
    float s2 = v.x * v.x + v.y * v.y + v.z * v.z + v.w * v.w;
#pragma unroll
    for (int d = 1; d < 64; d <<= 1) {
        s  += __shfl_xor(s,  d, 64);
        s2 += __shfl_xor(s2, d, 64);
    }
    float m   = s * (1.0f / 256.0f);
    float var = s2 * (1.0f / 256.0f) - m * m;
    float rr  = rsqrtf(var + 1e-5f);
    size_t orow = (size_t)((row >> 10) * TPAD + 4 + (row & 1023)) * D_;
    float vv[4] = {v.x, v.y, v.z, v.w};
#pragma unroll
    for (int k = 0; k < 4; k++) {
        int d = lane * 4 + k;
        outp[orow + d] = f2bf((vv[k] - m) * rr * bf2f(g[d]) + bf2f(bta[d]));
    }
}

__global__ void out_kernel(const float* __restrict__ X, const float* __restrict__ NP,
                           void* __restrict__ out, int out_size,
                           const int* __restrict__ flag) {
    int i = blockIdx.x * 256 + threadIdx.x;
    if (i >= out_size) return;
    const int n1 = MROWS * D_;
    float v = (i < n1) ? X[i] : NP[i - n1];
    if (*flag) ((u16*)out)[i] = f2bf(v);
    else       ((float*)out)[i] = v;
}

// ------------------------------- MFMA GEMM ---------------------------------
// C[M,N] = A[M,K] @ W^T, W: [N][K] bf16 row-major. 128x128 tile, BK=32,
// 256 threads (2x2 waves of 64x64, each 4x4 MFMA tiles of 16x16x32).
// AMAP: 0 = plain A[M][K];  1 = Hpad rows (K=256): row=(m>>10)*TPAD+4+(m&1023);
//       2 = Hpad im2col (K=2304): row=(m>>10)*TPAD+(m&1023)+kpos, col=kt&255.
// EPI:  0 = bf16 out (+bias); 1 = bf16 out (+bias, relu);
//       2 = fp32 out (+bias, +resid, *mask[row]).
template <int AMAP, int EPI>
__global__ __launch_bounds__(256)
void gemm_mfma(const u16* __restrict__ A, const u16* __restrict__ W,
               const u16* __restrict__ bias, const float* __restrict__ resid,
               const float* __restrict__ mask, void* __restrict__ Cp,
               int M, int N, int K) {
    __shared__ __align__(16) u16 As[128 * 32];
    __shared__ __align__(16) u16 Bs[128 * 32];
    const int tid  = threadIdx.x;
    const int wave = tid >> 6, lane = tid & 63;
    const int quad = lane >> 4, l15 = lane & 15;
    const int m0 = blockIdx.y * 128, n0 = blockIdx.x * 128;
    const int wm = (wave >> 1) * 64, wn = (wave & 1) * 64;
    const int srow = wave * 32;          // 32 rows staged per wave
    const int lr = lane >> 2, lc = (lane & 3) * 8;
    f32x4 acc[4][4] = {};

    for (int kt = 0; kt < K; kt += 32) {
#pragma unroll
        for (int half = 0; half < 2; half++) {
            int trow = srow + half * 16 + lr;          // tile-local row 0..127
            const u16* ga;
            if (AMAP == 0) {
                ga = A + (size_t)(m0 + trow) * K + kt + lc;
            } else if (AMAP == 1) {
                int m = m0 + trow;
                ga = A + (size_t)((m >> 10) * TPAD + 4 + (m & 1023)) * D_ + kt + lc;
            } else {
                int m = m0 + trow;
                ga = A + (size_t)((m >> 10) * TPAD + (m & 1023) + (kt >> 8)) * D_
                       + (kt & 255) + lc;
            }
            const u16* gb = W + (size_t)(n0 + trow) * K + kt + lc;
            glds16(ga, &As[(srow + half * 16) * 32]);
            glds16(gb, &Bs[(srow + half * 16) * 32]);
        }
        __builtin_amdgcn_s_waitcnt(0);
        __syncthreads();
        bf16x8 af[4], bfr[4];
#pragma unroll
        for (int i = 0; i < 4; i++)
            af[i] = *(const bf16x8*)&As[(wm + i * 16 + l15) * 32 + quad * 8];
#pragma unroll
        for (int j = 0; j < 4; j++)
            bfr[j] = *(const bf16x8*)&Bs[(wn + j * 16 + l15) * 32 + quad * 8];
#pragma unroll
        for (int i = 0; i < 4; i++)
#pragma unroll
            for (int j = 0; j < 4; j++)
                acc[i][j] = __builtin_amdgcn_mfma_f32_16x16x32_bf16(
                    af[i], bfr[j], acc[i][j], 0, 0, 0);
        __syncthreads();
    }

    float bv[4];
#pragma unroll
    for (int j = 0; j < 4; j++) bv[j] = bf2f(bias[n0 + wn + j * 16 + l15]);
#pragma unroll
    for (int i = 0; i < 4; i++) {
#pragma unroll
        for (int r = 0; r < 4; r++) {
            int m = m0 + wm + i * 16 + quad * 4 + r;
            float mk = (EPI == 2) ? mask[m] : 1.0f;
#pragma unroll
            for (int j = 0; j < 4; j++) {
                int n = n0 + wn + j * 16 + l15;
                float v = acc[i][j][r] + bv[j];
                if (EPI == 1) v = fmaxf(v, 0.0f);
                if (EPI == 2) {
                    v = (v + resid[(size_t)m * N + n]) * mk;
                    ((float*)Cp)[(size_t)m * N + n] = v;
                } else {
                    ((u16*)Cp)[(size_t)m * N + n] = f2bf(v);
                }
            }
        }
    }
}

// --------------------------- flash MFMA attention --------------------------
// QKV chunk-local [8192][768] bf16 (q|k|v, head h at cols h*128).
// Block: (qt 0..15, h 0..1, b 0..7), 256 threads. 64 queries/block
// (16/wave), K-tiles of 64 keys, online softmax, O -> Hpad bf16.
__global__ __launch_bounds__(256)
void attn_mfma(const u16* __restrict__ QKV, const float* __restrict__ NPc,
               u16* __restrict__ Hp) {
    __shared__ __align__(16) u16 Ks[64 * 136];    // K tile, padded stride
    __shared__ __align__(16) u16 Vt[128 * 72];    // V transposed [dk][key]
    __shared__ __align__(16) u16 Ps[4 * 16 * 72]; // P per wave, padded stride
    const int tid  = threadIdx.x;
    const int wave = tid >> 6, lane = tid & 63;
    const int quad = lane >> 4, l15 = lane & 15;
    const int qt = blockIdx.x, h = blockIdx.y, b = blockIdx.z;
    const int t0 = qt * 64;
    const float scale = 0.08838834764831845f;  // 1/sqrt(128)
    u16* Psw = Ps + wave * 16 * 72;

    bf16x8 q_a[4];
#pragma unroll
    for (int s = 0; s < 4; s++)
        q_a[s] = *(const bf16x8*)(QKV
            + (size_t)(b * 1024 + t0 + wave * 16 + l15) * 768
            + h * DK_ + s * 32 + quad * 8);

    float m_st[4], l_st[4];
    f32x4 oacc[8] = {};
#pragma unroll
    for (int r = 0; r < 4; r++) { m_st[r] = -1e30f; l_st[r] = 0.0f; }

    for (int kk = 0; kk < 16; kk++) {
        const int k0 = kk * 64;
        // ---- stage K tile and transposed V tile ----
#pragma unroll
        for (int p = 0; p < 4; p++) {
            int s = tid + p * 256;
            int key = s >> 4, dk0 = (s & 15) * 8;
            size_t grow = (size_t)(b * 1024 + k0 + key) * 768 + h * DK_;
            u16x8 kv = *(const u16x8*)(QKV + grow + 256 + dk0);
            *(u16x8*)&Ks[key * 136 + dk0] = kv;
            u16x8 vv = *(const u16x8*)(QKV + grow + 512 + dk0);
#pragma unroll
            for (int e = 0; e < 8; e++) Vt[(dk0 + e) * 72 + key] = vv[e];
        }
        __syncthreads();

        // ---- S = Q K^T (per wave: 16 q x 64 keys) ----
        f32x4 s4[4];
#pragma unroll
        for (int nt = 0; nt < 4; nt++) {
            f32x4 c = {0.f, 0.f, 0.f, 0.f};
#pragma unroll
            for (int s = 0; s < 4; s++) {
                bf16x8 kb = *(const bf16x8*)&Ks[(nt * 16 + l15) * 136 + s * 32 + quad * 8];
                c = __builtin_amdgcn_mfma_f32_16x16x32_bf16(q_a[s], kb, c, 0, 0, 0);
            }
            s4[nt] = c;
        }
        // ---- mask + scale ----
#pragma unroll
        for (int nt = 0; nt < 4; nt++) {
            float npv = NPc[b * 1024 + k0 + nt * 16 + l15];
            bool pad = (npv == 0.0f);
#pragma unroll
            for (int r = 0; r < 4; r++)
                s4[nt][r] = pad ? -1e30f : s4[nt][r] * scale;
        }
        // ---- online softmax update ----
        float alpha[4];
#pragma unroll
        for (int r = 0; r < 4; r++) {
            float v = fmaxf(fmaxf(s4[0][r], s4[1][r]), fmaxf(s4[2][r], s4[3][r]));
#pragma unroll
            for (int d = 1; d < 16; d <<= 1) v = fmaxf(v, __shfl_xor(v, d, 64));
            float mnew = fmaxf(m_st[r], v);
            alpha[r] = __expf(m_st[r] - mnew);
            m_st[r] = mnew;
            l_st[r] *= alpha[r];
        }
#pragma unroll
        for (int nt = 0; nt < 4; nt++)
#pragma unroll
            for (int r = 0; r < 4; r++) s4[nt][r] = __expf(s4[nt][r] - m_st[r]);
#pragma unroll
        for (int r = 0; r < 4; r++) {
            float v = s4[0][r] + s4[1][r] + s4[2][r] + s4[3][r];
#pragma unroll
            for (int d = 1; d < 16; d <<= 1) v += __shfl_xor(v, d, 64);
            l_st[r] += v;
        }
#pragma unroll
        for (int dt = 0; dt < 8; dt++)
#pragma unroll
            for (int r = 0; r < 4; r++) oacc[dt][r] *= alpha[r];
        // ---- P -> LDS (C-layout -> A-operand layout round-trip) ----
#pragma unroll
        for (int nt = 0; nt < 4; nt++)
#pragma unroll
            for (int r = 0; r < 4; r++)
                Psw[(quad * 4 + r) * 72 + nt * 16 + l15] = f2bf(s4[nt][r]);
        __syncthreads();
        // ---- O += P V ----
#pragma unroll
        for (int ks = 0; ks < 2; ks++) {
            bf16x8 pa = *(const bf16x8*)&Psw[l15 * 72 + ks * 32 + quad * 8];
#pragma unroll
            for (int dt = 0; dt < 8; dt++) {
                bf16x8 vb = *(const bf16x8*)&Vt[(dt * 16 + l15) * 72 + ks * 32 + quad * 8];
                oacc[dt] = __builtin_amdgcn_mfma_f32_16x16x32_bf16(pa, vb, oacc[dt], 0, 0, 0);
            }
        }
        __syncthreads();
    }

    // ---- epilogue: O / l -> Hpad ----
#pragma unroll
    for (int r = 0; r < 4; r++) {
        float inv = 1.0f / l_st[r];
        int t = t0 + wave * 16 + quad * 4 + r;
        size_t orow = (size_t)(b * TPAD + 4 + t) * D_ + h * DK_;
#pragma unroll
        for (int dt = 0; dt < 8; dt++)
            Hp[orow + dt * 16 + l15] = f2bf(oacc[dt][r] * inv);
    }
}

// ------------------------------- driver ------------------------------------

static inline int cdiv(int a, int b) { return (a + b - 1) / b; }

extern "C" void kernel_launch(void* const* d_in, const int* in_sizes, int n_in,
                              void* d_out, int out_size, void* d_ws, size_t ws_size,
                              hipStream_t stream) {
    const int* seq = (const int*)d_in[0];
    const int* pos = (const int*)d_in[1];
    (void)in_sizes; (void)n_in;

    unsigned char* w = (unsigned char*)d_ws;
    size_t off = 0;
    auto take = [&](size_t bytes) {
        unsigned char* p = w + off;
        off += (bytes + 255) & ~(size_t)255;
        return p;
    };
    int*   FLAG = (int*)  take(4);
    float* X    = (float*)take((size_t)MROWS * D_ * 4);       // 33.55 MB
    float* NP   = (float*)take((size_t)MROWS * 4);            //  0.13 MB
    u16*   Hpad = (u16*)  take((size_t)CHB_ * TPAD * D_ * 2); //  4.23 MB
    u16*   SCR  = (u16*)  take((size_t)CHR_ * DH_ * 2);       // 16.78 MB
    u16*   W1RC = (u16*)  take((size_t)DH_ * KCONV * 2);      //  4.72 MB
    u16*   WEMB = (u16*)  take((size_t)300 * D_ * 2);
    u16*   PEMB = (u16*)  take((size_t)3001 * D_ * 2);
    u16*   QKVW = (u16*)  take((size_t)L_ * 3 * D_ * D_ * 2);
    u16*   QKVB = (u16*)  take((size_t)L_ * 3 * D_ * 2);
    u16*   FCW  = (u16*)  take((size_t)L_ * D_ * D_ * 2);
    u16*   FCB  = (u16*)  take((size_t)L_ * D_ * 2);
    u16*   G1c  = (u16*)  take((size_t)L_ * D_ * 2);
    u16*   B1c  = (u16*)  take((size_t)L_ * D_ * 2);
    u16*   C1B  = (u16*)  take((size_t)L_ * DH_ * 2);
    u16*   C2W  = (u16*)  take((size_t)L_ * D_ * DH_ * 2);
    u16*   C2B  = (u16*)  take((size_t)L_ * D_ * 2);
    u16*   G2c  = (u16*)  take((size_t)L_ * D_ * 2);
    u16*   B2c  = (u16*)  take((size_t)L_ * D_ * 2);

    if (off > ws_size) {
        sentinel_kernel<<<cdiv(out_size, 256), 256, 0, stream>>>(d_out, out_size);
        return;
    }

    detect_kernel<<<1, 256, 0, stream>>>(d_in[2], FLAG);

    auto cvt = [&](const void* src, u16* dst, int n) {
        cvt_any_kernel<<<cdiv(n, 256), 256, 0, stream>>>(src, dst, n, FLAG);
    };
    cvt(d_in[2],  WEMB, 300 * D_);
    cvt(d_in[3],  PEMB, 3001 * D_);
    cvt(d_in[4],  QKVW, L_ * 3 * D_ * D_);
    cvt(d_in[5],  QKVB, L_ * 3 * D_);
    cvt(d_in[6],  FCW,  L_ * D_ * D_);
    cvt(d_in[7],  FCB,  L_ * D_);
    cvt(d_in[8],  G1c,  L_ * D_);
    cvt(d_in[9],  B1c,  L_ * D_);
    cvt(d_in[11], C1B,  L_ * DH_);
    cvt(d_in[12], C2W,  L_ * D_ * DH_);
    cvt(d_in[13], C2B,  L_ * D_);
    cvt(d_in[14], G2c,  L_ * D_);
    cvt(d_in[15], B2c,  L_ * D_);

    embed_kernel<<<MROWS, 256, 0, stream>>>(seq, pos, WEMB, PEMB, X, NP);

    for (int c = 0; c < NCH_; c++) {
        const size_t ro = (size_t)c * CHR_;
        zero_pad_kernel<<<64, 256, 0, stream>>>(Hpad);
        for (int l = 0; l < L_; l++) {
            // ---- attention sub-layer ----
            ln_kernel<<<CHR_ / 4, 256, 0, stream>>>(
                X + ro * D_, G1c + l * D_, B1c + l * D_, Hpad);
            gemm_mfma<1, 0><<<dim3(6, 64), 256, 0, stream>>>(
                Hpad, QKVW + (size_t)l * 3 * D_ * D_, QKVB + l * 3 * D_,
                nullptr, nullptr, SCR, CHR_, 3 * D_, D_);
            attn_mfma<<<dim3(16, NH_, CHB_), 256, 0, stream>>>(
                SCR, NP + ro, Hpad);
            gemm_mfma<1, 2><<<dim3(2, 64), 256, 0, stream>>>(
                Hpad, FCW + (size_t)l * D_ * D_, FCB + l * D_,
                X + ro * D_, NP + ro, X + ro * D_, CHR_, D_, D_);
            // ---- conv FFN sub-layer ----
            ln_kernel<<<CHR_ / 4, 256, 0, stream>>>(
                X + ro * D_, G2c + l * D_, B2c + l * D_, Hpad);
            {
                int n = DH_ * KCONV;
                w1_reorder2_kernel<<<cdiv(n, 256), 256, 0, stream>>>(
                    (const float*)d_in[10] + (size_t)l * DH_ * D_ * 9,
                    (const u16*)d_in[10] + (size_t)l * DH_ * D_ * 9,
                    W1RC, n, FLAG);
            }
            gemm_mfma<2, 1><<<dim3(8, 64), 256, 0, stream>>>(
                Hpad, W1RC, C1B + l * DH_,
                nullptr, nullptr, SCR, CHR_, DH_, KCONV);
            gemm_mfma<0, 2><<<dim3(2, 64), 256, 0, stream>>>(
                SCR, C2W + (size_t)l * D_ * DH_, C2B + l * D_,
                X + ro * D_, NP + ro, X + ro * D_, CHR_, D_, DH_);
        }
    }

    out_kernel<<<cdiv(out_size, 256), 256, 0, stream>>>(X, NP, d_out, out_size, FLAG);
}

// Round 5
// 1910.938 us; speedup vs baseline: 12.0130x; 1.7747x over previous
//
#include <hip/hip_runtime.h>

// ---------------------------------------------------------------------------
// FastSpeech-style encoder, round 4: attention bank-conflict fix (XOR-swizzled
// V^T), adaptive un-chunking (layout tiers picked by ws_size), layer-outer
// loop. B=32 T=1024 D=256 NH=2 dk=128 D_HID=1024 L=4, conv1 k9p4, conv2 k1.
// ---------------------------------------------------------------------------

#define B_ 32
#define T_ 1024
#define D_ 256
#define NH_ 2
#define DK_ 128
#define DH_ 1024
#define L_ 4
#define MROWS (B_ * T_)        // 32768
#define KCONV (D_ * 9)         // 2304
#define TPAD 1032              // 4 zero + 1024 + 4 zero rows per batch (Hpad)

typedef unsigned short u16;
typedef short bf16x8 __attribute__((ext_vector_type(8)));
typedef float f32x4 __attribute__((ext_vector_type(4)));
typedef u16 u16x8 __attribute__((ext_vector_type(8)));

__device__ __forceinline__ float bf2f(u16 h) {
    union { unsigned int u; float f; } a;
    a.u = ((unsigned int)h) << 16;
    return a.f;
}

__device__ __forceinline__ u16 f2bf(float f) {
    union { float f; unsigned int u; } a;
    a.f = f;
    unsigned int r = a.u + 0x7fffu + ((a.u >> 16) & 1u);  // RNE
    return (u16)(r >> 16);
}

__device__ __forceinline__ void glds16(const u16* g, u16* l) {
    __builtin_amdgcn_global_load_lds(
        (const __attribute__((address_space(1))) void*)g,
        (__attribute__((address_space(3))) void*)l, 16, 0, 0);
}

// --------------------------- dtype detection -------------------------------
__global__ void detect_kernel(const void* wemb_raw, int* flag) {
    __shared__ int cnt;
    if (threadIdx.x == 0) cnt = 0;
    __syncthreads();
    const u16* p = (const u16*)wemb_raw;
    if (p[256 + threadIdx.x] != 0) atomicAdd(&cnt, 1);
    __syncthreads();
    if (threadIdx.x == 0) *flag = (cnt >= 128) ? 1 : 0;   // 1 = bf16, 0 = fp32
}

__global__ void cvt_any_kernel(const void* __restrict__ src, u16* __restrict__ dst,
                               int n, const int* __restrict__ flag) {
    int i = blockIdx.x * 256 + threadIdx.x;
    if (i >= n) return;
    if (*flag) dst[i] = ((const u16*)src)[i];
    else       dst[i] = f2bf(((const float*)src)[i]);
}

// conv1 weights [l][oc][ic=256][kpos=9] -> [l][oc][kpos*256+ic] bf16 (n covers
// 1 or L layers; srcf/srch point at the first layer to convert)
__global__ void w1_reorder2_kernel(const float* __restrict__ srcf,
                                   const u16* __restrict__ srch,
                                   u16* __restrict__ out, int n,
                                   const int* __restrict__ flag) {
    int idx = blockIdx.x * 256 + threadIdx.x;
    if (idx >= n) return;
    int l  = idx / (DH_ * KCONV);
    int r  = idx % (DH_ * KCONV);
    int oc = r / KCONV;
    int kk = r % KCONV;
    int kpos = kk >> 8;
    int ic   = kk & 255;
    size_t si = (size_t)l * DH_ * D_ * 9 + (oc * D_ + ic) * 9 + kpos;
    out[idx] = (*flag) ? srch[si] : f2bf(srcf[si]);
}

__global__ void sentinel_kernel(void* out, int out_size) {
    int i = blockIdx.x * 256 + threadIdx.x;
    if (i < out_size) ((u16*)out)[i] = 0x42F6;  // 123.0 bf16 — "ws too small"
}

// --------------------------- small utility kernels -------------------------

__global__ void embed_kernel(const int* __restrict__ seq, const int* __restrict__ pos,
                             const u16* __restrict__ wemb, const u16* __restrict__ pemb,
                             float* __restrict__ X, float* __restrict__ NP) {
    int row = blockIdx.x;
    int d   = threadIdx.x;
    int s = seq[row];
    int p = pos[row];
    X[(size_t)row * D_ + d] = bf2f(wemb[s * D_ + d]) + bf2f(pemb[p * D_ + d]);
    if (d == 0) NP[row] = (s != 0) ? 1.0f : 0.0f;
}

// zero the 4-row borders of each batch in Hpad (rows 0..3 and 1028..1031)
__global__ void zero_pad_kernel(u16* __restrict__ Hp, int nb) {
    int i = blockIdx.x * 256 + threadIdx.x;          // nb*8*256
    if (i >= nb * 8 * 256) return;
    int b = i / (8 * 256);
    int r = (i / 256) & 7;
    int d = i & 255;
    int row = (r < 4) ? r : (1024 + r);
    Hp[(size_t)(b * TPAD + row) * D_ + d] = 0;
}

// LN: 4 rows/block (1 wave/row). x chunk-local fp32 [Mc][256];
// out -> Hpad layout: row -> (row>>10)*TPAD + 4 + (row&1023).
__global__ __launch_bounds__(256)
void ln_kernel(const float* __restrict__ x, const u16* __restrict__ g,
               const u16* __restrict__ bta, u16* __restrict__ outp) {
    int wave = threadIdx.x >> 6, lane = threadIdx.x & 63;
    int row = blockIdx.x * 4 + wave;
    const float* xr = x + (size_t)row * D_;
    float4 v = *(const float4*)&xr[lane * 4];
    float s  = v.x + v.y + v.z + v.w;
    float s2 = v.x * v.x + v.y * v.y + v.z * v.z + v.w * v.w;
#pragma unroll
    for (int d = 1; d < 64; d <<= 1) {
        s  += __shfl_xor(s,  d, 64);
        s2 += __shfl_xor(s2, d, 64);
    }
    float m   = s * (1.0f / 256.0f);
    float var = s2 * (1.0f / 256.0f) - m * m;
    float rr  = rsqrtf(var + 1e-5f);
    size_t orow = (size_t)((row >> 10) * TPAD + 4 + (row & 1023)) * D_;
    float vv[4] = {v.x, v.y, v.z, v.w};
#pragma unroll
    for (int k = 0; k < 4; k++) {
        int d = lane * 4 + k;
        outp[orow + d] = f2bf((vv[k] - m) * rr * bf2f(g[d]) + bf2f(bta[d]));
    }
}

__global__ void out_kernel(const float* __restrict__ X, const float* __restrict__ NP,
                           void* __restrict__ out, int out_size,
                           const int* __restrict__ flag) {
    int i = blockIdx.x * 256 + threadIdx.x;
    if (i >= out_size) return;
    const int n1 = MROWS * D_;
    float v = (i < n1) ? X[i] : NP[i - n1];
    if (*flag) ((u16*)out)[i] = f2bf(v);
    else       ((float*)out)[i] = v;
}

// ------------------------------- MFMA GEMM ---------------------------------
// C[M,N] = A[M,K] @ W^T, W: [N][K] bf16 row-major. 128x128 tile, BK=32,
// 256 threads (2x2 waves of 64x64, each 4x4 MFMA tiles of 16x16x32).
// AMAP: 0 plain A[M][K]; 1 Hpad rows (K=256); 2 Hpad im2col (K=2304).
// EPI:  0 bf16 (+bias); 1 bf16 (+bias, relu); 2 fp32 (+bias, +resid, *mask).
template <int AMAP, int EPI>
__global__ __launch_bounds__(256)
void gemm_mfma(const u16* __restrict__ A, const u16* __restrict__ W,
               const u16* __restrict__ bias, const float* __restrict__ resid,
               const float* __restrict__ mask, void* __restrict__ Cp,
               int M, int N, int K) {
    __shared__ __align__(16) u16 As[128 * 32];
    __shared__ __align__(16) u16 Bs[128 * 32];
    const int tid  = threadIdx.x;
    const int wave = tid >> 6, lane = tid & 63;
    const int quad = lane >> 4, l15 = lane & 15;
    const int m0 = blockIdx.y * 128, n0 = blockIdx.x * 128;
    const int wm = (wave >> 1) * 64, wn = (wave & 1) * 64;
    const int srow = wave * 32;
    const int lr = lane >> 2, lc = (lane & 3) * 8;
    f32x4 acc[4][4] = {};

    for (int kt = 0; kt < K; kt += 32) {
#pragma unroll
        for (int half = 0; half < 2; half++) {
            int trow = srow + half * 16 + lr;
            const u16* ga;
            if (AMAP == 0) {
                ga = A + (size_t)(m0 + trow) * K + kt + lc;
            } else if (AMAP == 1) {
                int m = m0 + trow;
                ga = A + (size_t)((m >> 10) * TPAD + 4 + (m & 1023)) * D_ + kt + lc;
            } else {
                int m = m0 + trow;
                ga = A + (size_t)((m >> 10) * TPAD + (m & 1023) + (kt >> 8)) * D_
                       + (kt & 255) + lc;
            }
            const u16* gb = W + (size_t)(n0 + trow) * K + kt + lc;
            glds16(ga, &As[(srow + half * 16) * 32]);
            glds16(gb, &Bs[(srow + half * 16) * 32]);
        }
        __builtin_amdgcn_s_waitcnt(0);
        __syncthreads();
        bf16x8 af[4], bfr[4];
#pragma unroll
        for (int i = 0; i < 4; i++)
            af[i] = *(const bf16x8*)&As[(wm + i * 16 + l15) * 32 + quad * 8];
#pragma unroll
        for (int j = 0; j < 4; j++)
            bfr[j] = *(const bf16x8*)&Bs[(wn + j * 16 + l15) * 32 + quad * 8];
#pragma unroll
        for (int i = 0; i < 4; i++)
#pragma unroll
            for (int j = 0; j < 4; j++)
                acc[i][j] = __builtin_amdgcn_mfma_f32_16x16x32_bf16(
                    af[i], bfr[j], acc[i][j], 0, 0, 0);
        __syncthreads();
    }

    float bv[4];
#pragma unroll
    for (int j = 0; j < 4; j++) bv[j] = bf2f(bias[n0 + wn + j * 16 + l15]);
#pragma unroll
    for (int i = 0; i < 4; i++) {
#pragma unroll
        for (int r = 0; r < 4; r++) {
            int m = m0 + wm + i * 16 + quad * 4 + r;
            float mk = (EPI == 2) ? mask[m] : 1.0f;
#pragma unroll
            for (int j = 0; j < 4; j++) {
                int n = n0 + wn + j * 16 + l15;
                float v = acc[i][j][r] + bv[j];
                if (EPI == 1) v = fmaxf(v, 0.0f);
                if (EPI == 2) {
                    v = (v + resid[(size_t)m * N + n]) * mk;
                    ((float*)Cp)[(size_t)m * N + n] = v;
                } else {
                    ((u16*)Cp)[(size_t)m * N + n] = f2bf(v);
                }
            }
        }
    }
}

// --------------------------- flash MFMA attention --------------------------
// QKV chunk-local [Mc][768] bf16 (q|k|v, head h at cols h*128).
// Block: (qt 0..15, h 0..1, b 0..cb-1), 256 threads, 64 q/block (16/wave),
// K-tiles of 64 keys, online softmax, O -> Hpad bf16.
// V^T LDS layout XOR-swizzled: col = key ^ (((d>>3)&7)<<3)  (conflict fix).
__global__ __launch_bounds__(256)
void attn_mfma(const u16* __restrict__ QKV, const float* __restrict__ NPg,
               u16* __restrict__ Hp) {
    __shared__ __align__(16) u16 Ks[64 * 136];
    __shared__ __align__(16) u16 Vt[128 * 72];
    __shared__ __align__(16) u16 Ps[4 * 16 * 72];
    __shared__ float npS[1024];
    const int tid  = threadIdx.x;
    const int wave = tid >> 6, lane = tid & 63;
    const int quad = lane >> 4, l15 = lane & 15;
    const int qt = blockIdx.x, h = blockIdx.y, b = blockIdx.z;
    const int t0 = qt * 64;
    const float scale = 0.08838834764831845f;  // 1/sqrt(128)
    u16* Psw = Ps + wave * 16 * 72;

    for (int i = tid; i < 1024; i += 256) npS[i] = NPg[b * 1024 + i];

    bf16x8 q_a[4];
#pragma unroll
    for (int s = 0; s < 4; s++)
        q_a[s] = *(const bf16x8*)(QKV
            + (size_t)(b * 1024 + t0 + wave * 16 + l15) * 768
            + h * DK_ + s * 32 + quad * 8);

    float m_st[4], l_st[4];
    f32x4 oacc[8] = {};
#pragma unroll
    for (int r = 0; r < 4; r++) { m_st[r] = -1e30f; l_st[r] = 0.0f; }

    for (int kk = 0; kk < 16; kk++) {
        const int k0 = kk * 64;
        if (kk) __syncthreads();   // prior tile's Ks/Vt reads complete
        // ---- stage K rows + swizzled V^T ----
#pragma unroll
        for (int p = 0; p < 4; p++) {
            int s = tid + p * 256;
            int key = s >> 4, dk0 = (s & 15) * 8;
            size_t grow = (size_t)(b * 1024 + k0 + key) * 768 + h * DK_;
            *(u16x8*)&Ks[key * 136 + dk0] = *(const u16x8*)(QKV + grow + 256 + dk0);
            u16x8 vv = *(const u16x8*)(QKV + grow + 512 + dk0);
            int colb = key ^ ((s & 7) << 3);   // swz = ((d>>3)&7)<<3, d=dk0+e
#pragma unroll
            for (int e = 0; e < 8; e++) Vt[(dk0 + e) * 72 + colb] = vv[e];
        }
        __syncthreads();

        // ---- S = Q K^T (per wave: 16 q x 64 keys) ----
        f32x4 s4[4];
#pragma unroll
        for (int nt = 0; nt < 4; nt++) {
            f32x4 c = {0.f, 0.f, 0.f, 0.f};
#pragma unroll
            for (int s = 0; s < 4; s++) {
                bf16x8 kb = *(const bf16x8*)&Ks[(nt * 16 + l15) * 136 + s * 32 + quad * 8];
                c = __builtin_amdgcn_mfma_f32_16x16x32_bf16(q_a[s], kb, c, 0, 0, 0);
            }
            s4[nt] = c;
        }
        // ---- mask + scale ----
#pragma unroll
        for (int nt = 0; nt < 4; nt++) {
            bool pad = (npS[k0 + nt * 16 + l15] == 0.0f);
#pragma unroll
            for (int r = 0; r < 4; r++)
                s4[nt][r] = pad ? -1e30f : s4[nt][r] * scale;
        }
        // ---- online softmax ----
        float alpha[4];
#pragma unroll
        for (int r = 0; r < 4; r++) {
            float v = fmaxf(fmaxf(s4[0][r], s4[1][r]), fmaxf(s4[2][r], s4[3][r]));
#pragma unroll
            for (int d = 1; d < 16; d <<= 1) v = fmaxf(v, __shfl_xor(v, d, 64));
            float mnew = fmaxf(m_st[r], v);
            alpha[r] = __expf(m_st[r] - mnew);
            m_st[r] = mnew;
            l_st[r] *= alpha[r];
        }
#pragma unroll
        for (int nt = 0; nt < 4; nt++)
#pragma unroll
            for (int r = 0; r < 4; r++) s4[nt][r] = __expf(s4[nt][r] - m_st[r]);
#pragma unroll
        for (int r = 0; r < 4; r++) {
            float v = s4[0][r] + s4[1][r] + s4[2][r] + s4[3][r];
#pragma unroll
            for (int d = 1; d < 16; d <<= 1) v += __shfl_xor(v, d, 64);
            l_st[r] += v;
        }
#pragma unroll
        for (int dt = 0; dt < 8; dt++)
#pragma unroll
            for (int r = 0; r < 4; r++) oacc[dt][r] *= alpha[r];
        // ---- P -> per-wave LDS (C-layout -> A-operand layout); wave-private,
        //      no block barrier needed ----
#pragma unroll
        for (int nt = 0; nt < 4; nt++)
#pragma unroll
            for (int r = 0; r < 4; r++)
                Psw[(quad * 4 + r) * 72 + nt * 16 + l15] = f2bf(s4[nt][r]);
        // ---- O += P V ----
#pragma unroll
        for (int ks = 0; ks < 2; ks++) {
            bf16x8 pa = *(const bf16x8*)&Psw[l15 * 72 + ks * 32 + quad * 8];
#pragma unroll
            for (int dt = 0; dt < 8; dt++) {
                int d = dt * 16 + l15;
                int swr = ((d >> 3) & 7) << 3;
                bf16x8 vb = *(const bf16x8*)&Vt[d * 72 + ((ks * 32 + quad * 8) ^ swr)];
                oacc[dt] = __builtin_amdgcn_mfma_f32_16x16x32_bf16(pa, vb, oacc[dt], 0, 0, 0);
            }
        }
    }

    // ---- epilogue: O / l -> Hpad ----
#pragma unroll
    for (int r = 0; r < 4; r++) {
        float inv = 1.0f / l_st[r];
        int t = t0 + wave * 16 + quad * 4 + r;
        size_t orow = (size_t)(b * TPAD + 4 + t) * D_ + h * DK_;
#pragma unroll
        for (int dt = 0; dt < 8; dt++)
            Hp[orow + dt * 16 + l15] = f2bf(oacc[dt][r] * inv);
    }
}

// ------------------------------- driver ------------------------------------

static inline int cdiv(int a, int b) { return (a + b - 1) / b; }

extern "C" void kernel_launch(void* const* d_in, const int* in_sizes, int n_in,
                              void* d_out, int out_size, void* d_ws, size_t ws_size,
                              hipStream_t stream) {
    const int* seq = (const int*)d_in[0];
    const int* pos = (const int*)d_in[1];
    (void)in_sizes; (void)n_in;

    // ---- adaptive layout: pick the largest tier that fits ws_size ----
    int   cb = 8, w1L = 1;     // tier C fallback (known-good footprint)
    int*   FLAG; float* X; float* NP; u16* Hpad; u16* SCR; u16* W1R;
    u16 *WEMB, *PEMB, *QKVW, *QKVB, *FCW, *FCB, *G1c, *B1c, *C1B, *C2W, *C2B, *G2c, *B2c;

    unsigned char* wsb = (unsigned char*)d_ws;
    size_t off;
    auto build = [&](int cb_, int w1L_) -> size_t {
        off = 0;
        auto take = [&](size_t bytes) {
            unsigned char* p = wsb + off;
            off += (bytes + 255) & ~(size_t)255;
            return p;
        };
        FLAG = (int*)  take(4);
        X    = (float*)take((size_t)MROWS * D_ * 4);
        NP   = (float*)take((size_t)MROWS * 4);
        Hpad = (u16*)  take((size_t)cb_ * TPAD * D_ * 2);
        SCR  = (u16*)  take((size_t)cb_ * T_ * DH_ * 2);
        W1R  = (u16*)  take((size_t)w1L_ * DH_ * KCONV * 2);
        WEMB = (u16*)  take((size_t)300 * D_ * 2);
        PEMB = (u16*)  take((size_t)3001 * D_ * 2);
        QKVW = (u16*)  take((size_t)L_ * 3 * D_ * D_ * 2);
        QKVB = (u16*)  take((size_t)L_ * 3 * D_ * 2);
        FCW  = (u16*)  take((size_t)L_ * D_ * D_ * 2);
        FCB  = (u16*)  take((size_t)L_ * D_ * 2);
        G1c  = (u16*)  take((size_t)L_ * D_ * 2);
        B1c  = (u16*)  take((size_t)L_ * D_ * 2);
        C1B  = (u16*)  take((size_t)L_ * DH_ * 2);
        C2W  = (u16*)  take((size_t)L_ * D_ * DH_ * 2);
        C2B  = (u16*)  take((size_t)L_ * D_ * 2);
        G2c  = (u16*)  take((size_t)L_ * D_ * 2);
        B2c  = (u16*)  take((size_t)L_ * D_ * 2);
        return off;
    };
    if      (build(32, L_) <= ws_size) { cb = 32; w1L = L_; }  // tier A ~140MB
    else if (build(8,  L_) <= ws_size) { cb = 8;  w1L = L_; }  // tier B ~77MB
    else if (build(8,  1)  <= ws_size) { cb = 8;  w1L = 1;  }  // tier C ~63MB
    else {
        sentinel_kernel<<<cdiv(out_size, 256), 256, 0, stream>>>(d_out, out_size);
        return;
    }
    const int nch = B_ / cb;
    const int Mc  = cb * T_;

    detect_kernel<<<1, 256, 0, stream>>>(d_in[2], FLAG);
    auto cvt = [&](const void* src, u16* dst, int n) {
        cvt_any_kernel<<<cdiv(n, 256), 256, 0, stream>>>(src, dst, n, FLAG);
    };
    cvt(d_in[2],  WEMB, 300 * D_);
    cvt(d_in[3],  PEMB, 3001 * D_);
    cvt(d_in[4],  QKVW, L_ * 3 * D_ * D_);
    cvt(d_in[5],  QKVB, L_ * 3 * D_);
    cvt(d_in[6],  FCW,  L_ * D_ * D_);
    cvt(d_in[7],  FCB,  L_ * D_);
    cvt(d_in[8],  G1c,  L_ * D_);
    cvt(d_in[9],  B1c,  L_ * D_);
    cvt(d_in[11], C1B,  L_ * DH_);
    cvt(d_in[12], C2W,  L_ * D_ * DH_);
    cvt(d_in[13], C2B,  L_ * D_);
    cvt(d_in[14], G2c,  L_ * D_);
    cvt(d_in[15], B2c,  L_ * D_);
    if (w1L == L_) {
        int n = L_ * DH_ * KCONV;
        w1_reorder2_kernel<<<cdiv(n, 256), 256, 0, stream>>>(
            (const float*)d_in[10], (const u16*)d_in[10], W1R, n, FLAG);
    }

    embed_kernel<<<MROWS, 256, 0, stream>>>(seq, pos, WEMB, PEMB, X, NP);
    zero_pad_kernel<<<cb * 8, 256, 0, stream>>>(Hpad, cb);

    for (int l = 0; l < L_; l++) {
        // ---- attention sub-layer ----
        for (int c = 0; c < nch; c++) {
            const size_t ro = (size_t)c * Mc;
            ln_kernel<<<Mc / 4, 256, 0, stream>>>(
                X + ro * D_, G1c + l * D_, B1c + l * D_, Hpad);
            gemm_mfma<1, 0><<<dim3(6, Mc / 128), 256, 0, stream>>>(
                Hpad, QKVW + (size_t)l * 3 * D_ * D_, QKVB + l * 3 * D_,
                nullptr, nullptr, SCR, Mc, 3 * D_, D_);
            attn_mfma<<<dim3(16, NH_, cb), 256, 0, stream>>>(
                SCR, NP + ro, Hpad);
            gemm_mfma<1, 2><<<dim3(2, Mc / 128), 256, 0, stream>>>(
                Hpad, FCW + (size_t)l * D_ * D_, FCB + l * D_,
                X + ro * D_, NP + ro, X + ro * D_, Mc, D_, D_);
        }
        // ---- conv FFN sub-layer ----
        const u16* w1p = W1R + (w1L == L_ ? (size_t)l * DH_ * KCONV : 0);
        if (w1L != L_) {
            int n = DH_ * KCONV;
            w1_reorder2_kernel<<<cdiv(n, 256), 256, 0, stream>>>(
                (const float*)d_in[10] + (size_t)l * DH_ * D_ * 9,
                (const u16*)d_in[10] + (size_t)l * DH_ * D_ * 9,
                W1R, n, FLAG);
        }
        for (int c = 0; c < nch; c++) {
            const size_t ro = (size_t)c * Mc;
            ln_kernel<<<Mc / 4, 256, 0, stream>>>(
                X + ro * D_, G2c + l * D_, B2c + l * D_, Hpad);
            gemm_mfma<2, 1><<<dim3(8, Mc / 128), 256, 0, stream>>>(
                Hpad, w1p, C1B + l * DH_,
                nullptr, nullptr, SCR, Mc, DH_, KCONV);
            gemm_mfma<0, 2><<<dim3(2, Mc / 128), 256, 0, stream>>>(
                SCR, C2W + (size_t)l * D_ * DH_, C2B + l * D_,
                X + ro * D_, NP + ro, X + ro * D_, Mc, D_, DH_);
        }
    }

    out_kernel<<<cdiv(out_size, 256), 256, 0, stream>>>(X, NP, d_out, out_size, FLAG);
}

// Round 6
// 1826.681 us; speedup vs baseline: 12.5671x; 1.0461x over previous
//
#include <hip/hip_runtime.h>

// ---------------------------------------------------------------------------
// FastSpeech-style encoder, round 5:
//  (a) conv1 im2col k-order ic-outer/kpos-inner (L2 reuse-distance fix;
//      round-4 FETCH was 530MB vs 22MB unique -> L2 thrash),
//  (b) XOR column-group swizzle in GEMM LDS staging/reads (8-way -> 2-way
//      bank aliasing; 1.9e7 SQ_LDS_BANK_CONFLICT observed).
// B=32 T=1024 D=256 NH=2 dk=128 D_HID=1024 L=4, conv1 k9p4, conv2 k1.
// ---------------------------------------------------------------------------

#define B_ 32
#define T_ 1024
#define D_ 256
#define NH_ 2
#define DK_ 128
#define DH_ 1024
#define L_ 4
#define MROWS (B_ * T_)        // 32768
#define KCONV (D_ * 9)         // 2304
#define TPAD 1032              // 4 zero + 1024 + 4 zero rows per batch (Hpad)

typedef unsigned short u16;
typedef short bf16x8 __attribute__((ext_vector_type(8)));
typedef float f32x4 __attribute__((ext_vector_type(4)));
typedef u16 u16x8 __attribute__((ext_vector_type(8)));

__device__ __forceinline__ float bf2f(u16 h) {
    union { unsigned int u; float f; } a;
    a.u = ((unsigned int)h) << 16;
    return a.f;
}

__device__ __forceinline__ u16 f2bf(float f) {
    union { float f; unsigned int u; } a;
    a.f = f;
    unsigned int r = a.u + 0x7fffu + ((a.u >> 16) & 1u);  // RNE
    return (u16)(r >> 16);
}

__device__ __forceinline__ void glds16(const u16* g, u16* l) {
    __builtin_amdgcn_global_load_lds(
        (const __attribute__((address_space(1))) void*)g,
        (__attribute__((address_space(3))) void*)l, 16, 0, 0);
}

__device__ __forceinline__ int swz4(int r) { return (r ^ (r >> 2)) & 3; }

// --------------------------- dtype detection -------------------------------
__global__ void detect_kernel(const void* wemb_raw, int* flag) {
    __shared__ int cnt;
    if (threadIdx.x == 0) cnt = 0;
    __syncthreads();
    const u16* p = (const u16*)wemb_raw;
    if (p[256 + threadIdx.x] != 0) atomicAdd(&cnt, 1);
    __syncthreads();
    if (threadIdx.x == 0) *flag = (cnt >= 128) ? 1 : 0;   // 1 = bf16, 0 = fp32
}

__global__ void cvt_any_kernel(const void* __restrict__ src, u16* __restrict__ dst,
                               int n, const int* __restrict__ flag) {
    int i = blockIdx.x * 256 + threadIdx.x;
    if (i >= n) return;
    if (*flag) dst[i] = ((const u16*)src)[i];
    else       dst[i] = f2bf(((const float*)src)[i]);
}

// conv1 weights [l][oc][ic=256][kpos=9] -> [l][oc][kpos*256+ic] bf16
__global__ void w1_reorder2_kernel(const float* __restrict__ srcf,
                                   const u16* __restrict__ srch,
                                   u16* __restrict__ out, int n,
                                   const int* __restrict__ flag) {
    int idx = blockIdx.x * 256 + threadIdx.x;
    if (idx >= n) return;
    int l  = idx / (DH_ * KCONV);
    int r  = idx % (DH_ * KCONV);
    int oc = r / KCONV;
    int kk = r % KCONV;
    int kpos = kk >> 8;
    int ic   = kk & 255;
    size_t si = (size_t)l * DH_ * D_ * 9 + (oc * D_ + ic) * 9 + kpos;
    out[idx] = (*flag) ? srch[si] : f2bf(srcf[si]);
}

__global__ void sentinel_kernel(void* out, int out_size) {
    int i = blockIdx.x * 256 + threadIdx.x;
    if (i < out_size) ((u16*)out)[i] = 0x42F6;  // 123.0 bf16 — "ws too small"
}

// --------------------------- small utility kernels -------------------------

__global__ void embed_kernel(const int* __restrict__ seq, const int* __restrict__ pos,
                             const u16* __restrict__ wemb, const u16* __restrict__ pemb,
                             float* __restrict__ X, float* __restrict__ NP) {
    int row = blockIdx.x;
    int d   = threadIdx.x;
    int s = seq[row];
    int p = pos[row];
    X[(size_t)row * D_ + d] = bf2f(wemb[s * D_ + d]) + bf2f(pemb[p * D_ + d]);
    if (d == 0) NP[row] = (s != 0) ? 1.0f : 0.0f;
}

__global__ void zero_pad_kernel(u16* __restrict__ Hp, int nb) {
    int i = blockIdx.x * 256 + threadIdx.x;
    if (i >= nb * 8 * 256) return;
    int b = i / (8 * 256);
    int r = (i / 256) & 7;
    int d = i & 255;
    int row = (r < 4) ? r : (1024 + r);
    Hp[(size_t)(b * TPAD + row) * D_ + d] = 0;
}

// LN: 4 rows/block (1 wave/row); out -> Hpad layout.
__global__ __launch_bounds__(256)
void ln_kernel(const float* __restrict__ x, const u16* __restrict__ g,
               const u16* __restrict__ bta, u16* __restrict__ outp) {
    int wave = threadIdx.x >> 6, lane = threadIdx.x & 63;
    int row = blockIdx.x * 4 + wave;
    const float* xr = x + (size_t)row * D_;
    float4 v = *(const float4*)&xr[lane * 4];
    float s  = v.x + v.y + v.z + v.w;
    float s2 = v.x * v.x + v.y * v.y + v.z * v.z + v.w * v.w;
#pragma unroll
    for (int d = 1; d < 64; d <<= 1) {
        s  += __shfl_xor(s,  d, 64);
        s2 += __shfl_xor(s2, d, 64);
    }
    float m   = s * (1.0f / 256.0f);
    float var = s2 * (1.0f / 256.0f) - m * m;
    float rr  = rsqrtf(var + 1e-5f);
    size_t orow = (size_t)((row >> 10) * TPAD + 4 + (row & 1023)) * D_;
    float vv[4] = {v.x, v.y, v.z, v.w};
#pragma unroll
    for (int k = 0; k < 4; k++) {
        int d = lane * 4 + k;
        outp[orow + d] = f2bf((vv[k] - m) * rr * bf2f(g[d]) + bf2f(bta[d]));
    }
}

__global__ void out_kernel(const float* __restrict__ X, const float* __restrict__ NP,
                           void* __restrict__ out, int out_size,
                           const int* __restrict__ flag) {
    int i = blockIdx.x * 256 + threadIdx.x;
    if (i >= out_size) return;
    const int n1 = MROWS * D_;
    float v = (i < n1) ? X[i] : NP[i - n1];
    if (*flag) ((u16*)out)[i] = f2bf(v);
    else       ((float*)out)[i] = v;
}

// ------------------------------- MFMA GEMM ---------------------------------
// C[M,N] = A[M,K] @ W^T, W: [N][K] bf16 row-major. 128x128 tile, BK=32,
// 256 threads (2x2 waves of 64x64, each 4x4 MFMA tiles of 16x16x32).
// AMAP: 0 plain A[M][K]; 1 Hpad rows (K=256); 2 Hpad im2col (K=2304,
//       k-tiles enumerated ic-outer/kpos-inner for L2 reuse).
// EPI:  0 bf16 (+bias); 1 bf16 (+bias, relu); 2 fp32 (+bias, +resid, *mask).
// LDS column-group XOR swizzle: staged group g = lg ^ swz4(lr); reads use
// quad ^ swz4(l15)  -> <=2-way bank aliasing (free).
template <int AMAP, int EPI>
__global__ __launch_bounds__(256)
void gemm_mfma(const u16* __restrict__ A, const u16* __restrict__ W,
               const u16* __restrict__ bias, const float* __restrict__ resid,
               const float* __restrict__ mask, void* __restrict__ Cp,
               int M, int N, int K) {
    __shared__ __align__(16) u16 As[128 * 32];
    __shared__ __align__(16) u16 Bs[128 * 32];
    const int tid  = threadIdx.x;
    const int wave = tid >> 6, lane = tid & 63;
    const int quad = lane >> 4, l15 = lane & 15;
    const int m0 = blockIdx.y * 128, n0 = blockIdx.x * 128;
    const int wm = (wave >> 1) * 64, wn = (wave & 1) * 64;
    const int srow = wave * 32;
    const int lr = lane >> 2;                 // row within 16-row stage group
    const int lc = (lane & 3) * 8;            // unswizzled col group offset
    const int lcs = (((lane & 3) ^ swz4(lr)) * 8);  // swizzled col group
    const int rq  = (quad ^ swz4(l15)) * 8;         // swizzled read group
    f32x4 acc[4][4] = {};

    const int nkt = K / 32;
    for (int t = 0; t < nkt; t++) {
        int kt;
        if (AMAP == 2) { int kpos = t % 9, ict = t / 9; kt = kpos * 256 + ict * 32; }
        else           { kt = t * 32; }
#pragma unroll
        for (int half = 0; half < 2; half++) {
            int trow = srow + half * 16 + lr;
            const u16* ga;
            if (AMAP == 0) {
                ga = A + (size_t)(m0 + trow) * K + kt + lcs;
            } else if (AMAP == 1) {
                int m = m0 + trow;
                ga = A + (size_t)((m >> 10) * TPAD + 4 + (m & 1023)) * D_ + kt + lcs;
            } else {
                int m = m0 + trow;
                ga = A + (size_t)((m >> 10) * TPAD + (m & 1023) + (kt >> 8)) * D_
                       + (kt & 255) + lcs;
            }
            const u16* gb = W + (size_t)(n0 + trow) * K + kt + lcs;
            glds16(ga, &As[(srow + half * 16) * 32]);
            glds16(gb, &Bs[(srow + half * 16) * 32]);
        }
        __builtin_amdgcn_s_waitcnt(0);
        __syncthreads();
        bf16x8 af[4], bfr[4];
#pragma unroll
        for (int i = 0; i < 4; i++)
            af[i] = *(const bf16x8*)&As[(wm + i * 16 + l15) * 32 + rq];
#pragma unroll
        for (int j = 0; j < 4; j++)
            bfr[j] = *(const bf16x8*)&Bs[(wn + j * 16 + l15) * 32 + rq];
#pragma unroll
        for (int i = 0; i < 4; i++)
#pragma unroll
            for (int j = 0; j < 4; j++)
                acc[i][j] = __builtin_amdgcn_mfma_f32_16x16x32_bf16(
                    af[i], bfr[j], acc[i][j], 0, 0, 0);
        __syncthreads();
    }
    (void)lc;

    float bv[4];
#pragma unroll
    for (int j = 0; j < 4; j++) bv[j] = bf2f(bias[n0 + wn + j * 16 + l15]);
#pragma unroll
    for (int i = 0; i < 4; i++) {
#pragma unroll
        for (int r = 0; r < 4; r++) {
            int m = m0 + wm + i * 16 + quad * 4 + r;
            float mk = (EPI == 2) ? mask[m] : 1.0f;
#pragma unroll
            for (int j = 0; j < 4; j++) {
                int n = n0 + wn + j * 16 + l15;
                float v = acc[i][j][r] + bv[j];
                if (EPI == 1) v = fmaxf(v, 0.0f);
                if (EPI == 2) {
                    v = (v + resid[(size_t)m * N + n]) * mk;
                    ((float*)Cp)[(size_t)m * N + n] = v;
                } else {
                    ((u16*)Cp)[(size_t)m * N + n] = f2bf(v);
                }
            }
        }
    }
}

// --------------------------- flash MFMA attention --------------------------
__global__ __launch_bounds__(256)
void attn_mfma(const u16* __restrict__ QKV, const float* __restrict__ NPg,
               u16* __restrict__ Hp) {
    __shared__ __align__(16) u16 Ks[64 * 136];
    __shared__ __align__(16) u16 Vt[128 * 72];
    __shared__ __align__(16) u16 Ps[4 * 16 * 72];
    __shared__ float npS[1024];
    const int tid  = threadIdx.x;
    const int wave = tid >> 6, lane = tid & 63;
    const int quad = lane >> 4, l15 = lane & 15;
    const int qt = blockIdx.x, h = blockIdx.y, b = blockIdx.z;
    const int t0 = qt * 64;
    const float scale = 0.08838834764831845f;  // 1/sqrt(128)
    u16* Psw = Ps + wave * 16 * 72;

    for (int i = tid; i < 1024; i += 256) npS[i] = NPg[b * 1024 + i];

    bf16x8 q_a[4];
#pragma unroll
    for (int s = 0; s < 4; s++)
        q_a[s] = *(const bf16x8*)(QKV
            + (size_t)(b * 1024 + t0 + wave * 16 + l15) * 768
            + h * DK_ + s * 32 + quad * 8);

    float m_st[4], l_st[4];
    f32x4 oacc[8] = {};
#pragma unroll
    for (int r = 0; r < 4; r++) { m_st[r] = -1e30f; l_st[r] = 0.0f; }

    for (int kk = 0; kk < 16; kk++) {
        const int k0 = kk * 64;
        if (kk) __syncthreads();
#pragma unroll
        for (int p = 0; p < 4; p++) {
            int s = tid + p * 256;
            int key = s >> 4, dk0 = (s & 15) * 8;
            size_t grow = (size_t)(b * 1024 + k0 + key) * 768 + h * DK_;
            *(u16x8*)&Ks[key * 136 + dk0] = *(const u16x8*)(QKV + grow + 256 + dk0);
            u16x8 vv = *(const u16x8*)(QKV + grow + 512 + dk0);
            int colb = key ^ ((s & 7) << 3);
#pragma unroll
            for (int e = 0; e < 8; e++) Vt[(dk0 + e) * 72 + colb] = vv[e];
        }
        __syncthreads();

        f32x4 s4[4];
#pragma unroll
        for (int nt = 0; nt < 4; nt++) {
            f32x4 c = {0.f, 0.f, 0.f, 0.f};
#pragma unroll
            for (int s = 0; s < 4; s++) {
                bf16x8 kb = *(const bf16x8*)&Ks[(nt * 16 + l15) * 136 + s * 32 + quad * 8];
                c = __builtin_amdgcn_mfma_f32_16x16x32_bf16(q_a[s], kb, c, 0, 0, 0);
            }
            s4[nt] = c;
        }
#pragma unroll
        for (int nt = 0; nt < 4; nt++) {
            bool pad = (npS[k0 + nt * 16 + l15] == 0.0f);
#pragma unroll
            for (int r = 0; r < 4; r++)
                s4[nt][r] = pad ? -1e30f : s4[nt][r] * scale;
        }
        float alpha[4];
#pragma unroll
        for (int r = 0; r < 4; r++) {
            float v = fmaxf(fmaxf(s4[0][r], s4[1][r]), fmaxf(s4[2][r], s4[3][r]));
#pragma unroll
            for (int d = 1; d < 16; d <<= 1) v = fmaxf(v, __shfl_xor(v, d, 64));
            float mnew = fmaxf(m_st[r], v);
            alpha[r] = __expf(m_st[r] - mnew);
            m_st[r] = mnew;
            l_st[r] *= alpha[r];
        }
#pragma unroll
        for (int nt = 0; nt < 4; nt++)
#pragma unroll
            for (int r = 0; r < 4; r++) s4[nt][r] = __expf(s4[nt][r] - m_st[r]);
#pragma unroll
        for (int r = 0; r < 4; r++) {
            float v = s4[0][r] + s4[1][r] + s4[2][r] + s4[3][r];
#pragma unroll
            for (int d = 1; d < 16; d <<= 1) v += __shfl_xor(v, d, 64);
            l_st[r] += v;
        }
#pragma unroll
        for (int dt = 0; dt < 8; dt++)
#pragma unroll
            for (int r = 0; r < 4; r++) oacc[dt][r] *= alpha[r];
#pragma unroll
        for (int nt = 0; nt < 4; nt++)
#pragma unroll
            for (int r = 0; r < 4; r++)
                Psw[(quad * 4 + r) * 72 + nt * 16 + l15] = f2bf(s4[nt][r]);
#pragma unroll
        for (int ks = 0; ks < 2; ks++) {
            bf16x8 pa = *(const bf16x8*)&Psw[l15 * 72 + ks * 32 + quad * 8];
#pragma unroll
            for (int dt = 0; dt < 8; dt++) {
                int d = dt * 16 + l15;
                int swr = ((d >> 3) & 7) << 3;
                bf16x8 vb = *(const bf16x8*)&Vt[d * 72 + ((ks * 32 + quad * 8) ^ swr)];
                oacc[dt] = __builtin_amdgcn_mfma_f32_16x16x32_bf16(pa, vb, oacc[dt], 0, 0, 0);
            }
        }
    }

#pragma unroll
    for (int r = 0; r < 4; r++) {
        float inv = 1.0f / l_st[r];
        int t = t0 + wave * 16 + quad * 4 + r;
        size_t orow = (size_t)(b * TPAD + 4 + t) * D_ + h * DK_;
#pragma unroll
        for (int dt = 0; dt < 8; dt++)
            Hp[orow + dt * 16 + l15] = f2bf(oacc[dt][r] * inv);
    }
}

// ------------------------------- driver ------------------------------------

static inline int cdiv(int a, int b) { return (a + b - 1) / b; }

extern "C" void kernel_launch(void* const* d_in, const int* in_sizes, int n_in,
                              void* d_out, int out_size, void* d_ws, size_t ws_size,
                              hipStream_t stream) {
    const int* seq = (const int*)d_in[0];
    const int* pos = (const int*)d_in[1];
    (void)in_sizes; (void)n_in;

    int   cb = 8, w1L = 1;
    int*   FLAG; float* X; float* NP; u16* Hpad; u16* SCR; u16* W1R;
    u16 *WEMB, *PEMB, *QKVW, *QKVB, *FCW, *FCB, *G1c, *B1c, *C1B, *C2W, *C2B, *G2c, *B2c;

    unsigned char* wsb = (unsigned char*)d_ws;
    size_t off;
    auto build = [&](int cb_, int w1L_) -> size_t {
        off = 0;
        auto take = [&](size_t bytes) {
            unsigned char* p = wsb + off;
            off += (bytes + 255) & ~(size_t)255;
            return p;
        };
        FLAG = (int*)  take(4);
        X    = (float*)take((size_t)MROWS * D_ * 4);
        NP   = (float*)take((size_t)MROWS * 4);
        Hpad = (u16*)  take((size_t)cb_ * TPAD * D_ * 2);
        SCR  = (u16*)  take((size_t)cb_ * T_ * DH_ * 2);
        W1R  = (u16*)  take((size_t)w1L_ * DH_ * KCONV * 2);
        WEMB = (u16*)  take((size_t)300 * D_ * 2);
        PEMB = (u16*)  take((size_t)3001 * D_ * 2);
        QKVW = (u16*)  take((size_t)L_ * 3 * D_ * D_ * 2);
        QKVB = (u16*)  take((size_t)L_ * 3 * D_ * 2);
        FCW  = (u16*)  take((size_t)L_ * D_ * D_ * 2);
        FCB  = (u16*)  take((size_t)L_ * D_ * 2);
        G1c  = (u16*)  take((size_t)L_ * D_ * 2);
        B1c  = (u16*)  take((size_t)L_ * D_ * 2);
        C1B  = (u16*)  take((size_t)L_ * DH_ * 2);
        C2W  = (u16*)  take((size_t)L_ * D_ * DH_ * 2);
        C2B  = (u16*)  take((size_t)L_ * D_ * 2);
        G2c  = (u16*)  take((size_t)L_ * D_ * 2);
        B2c  = (u16*)  take((size_t)L_ * D_ * 2);
        return off;
    };
    if      (build(32, L_) <= ws_size) { cb = 32; w1L = L_; }
    else if (build(8,  L_) <= ws_size) { cb = 8;  w1L = L_; }
    else if (build(8,  1)  <= ws_size) { cb = 8;  w1L = 1;  }
    else {
        sentinel_kernel<<<cdiv(out_size, 256), 256, 0, stream>>>(d_out, out_size);
        return;
    }
    const int nch = B_ / cb;
    const int Mc  = cb * T_;

    detect_kernel<<<1, 256, 0, stream>>>(d_in[2], FLAG);
    auto cvt = [&](const void* src, u16* dst, int n) {
        cvt_any_kernel<<<cdiv(n, 256), 256, 0, stream>>>(src, dst, n, FLAG);
    };
    cvt(d_in[2],  WEMB, 300 * D_);
    cvt(d_in[3],  PEMB, 3001 * D_);
    cvt(d_in[4],  QKVW, L_ * 3 * D_ * D_);
    cvt(d_in[5],  QKVB, L_ * 3 * D_);
    cvt(d_in[6],  FCW,  L_ * D_ * D_);
    cvt(d_in[7],  FCB,  L_ * D_);
    cvt(d_in[8],  G1c,  L_ * D_);
    cvt(d_in[9],  B1c,  L_ * D_);
    cvt(d_in[11], C1B,  L_ * DH_);
    cvt(d_in[12], C2W,  L_ * D_ * DH_);
    cvt(d_in[13], C2B,  L_ * D_);
    cvt(d_in[14], G2c,  L_ * D_);
    cvt(d_in[15], B2c,  L_ * D_);
    if (w1L == L_) {
        int n = L_ * DH_ * KCONV;
        w1_reorder2_kernel<<<cdiv(n, 256), 256, 0, stream>>>(
            (const float*)d_in[10], (const u16*)d_in[10], W1R, n, FLAG);
    }

    embed_kernel<<<MROWS, 256, 0, stream>>>(seq, pos, WEMB, PEMB, X, NP);
    zero_pad_kernel<<<cb * 8, 256, 0, stream>>>(Hpad, cb);

    for (int l = 0; l < L_; l++) {
        for (int c = 0; c < nch; c++) {
            const size_t ro = (size_t)c * Mc;
            ln_kernel<<<Mc / 4, 256, 0, stream>>>(
                X + ro * D_, G1c + l * D_, B1c + l * D_, Hpad);
            gemm_mfma<1, 0><<<dim3(6, Mc / 128), 256, 0, stream>>>(
                Hpad, QKVW + (size_t)l * 3 * D_ * D_, QKVB + l * 3 * D_,
                nullptr, nullptr, SCR, Mc, 3 * D_, D_);
            attn_mfma<<<dim3(16, NH_, cb), 256, 0, stream>>>(
                SCR, NP + ro, Hpad);
            gemm_mfma<1, 2><<<dim3(2, Mc / 128), 256, 0, stream>>>(
                Hpad, FCW + (size_t)l * D_ * D_, FCB + l * D_,
                X + ro * D_, NP + ro, X + ro * D_, Mc, D_, D_);
        }
        const u16* w1p = W1R + (w1L == L_ ? (size_t)l * DH_ * KCONV : 0);
        if (w1L != L_) {
            int n = DH_ * KCONV;
            w1_reorder2_kernel<<<cdiv(n, 256), 256, 0, stream>>>(
                (const float*)d_in[10] + (size_t)l * DH_ * D_ * 9,
                (const u16*)d_in[10] + (size_t)l * DH_ * D_ * 9,
                W1R, n, FLAG);
        }
        for (int c = 0; c < nch; c++) {
            const size_t ro = (size_t)c * Mc;
            ln_kernel<<<Mc / 4, 256, 0, stream>>>(
                X + ro * D_, G2c + l * D_, B2c + l * D_, Hpad);
            gemm_mfma<2, 1><<<dim3(8, Mc / 128), 256, 0, stream>>>(
                Hpad, w1p, C1B + l * DH_,
                nullptr, nullptr, SCR, Mc, DH_, KCONV);
            gemm_mfma<0, 2><<<dim3(2, Mc / 128), 256, 0, stream>>>(
                SCR, C2W + (size_t)l * D_ * DH_, C2B + l * D_,
                X + ro * D_, NP + ro, X + ro * D_, Mc, D_, DH_);
        }
    }

    out_kernel<<<cdiv(out_size, 256), 256, 0, stream>>>(X, NP, d_out, out_size, FLAG);
}